// Round 14
// baseline (948.665 us; speedup 1.0000x reference)
//
#include <hip/hip_runtime.h>

typedef unsigned short ushort_t;
typedef _Float16 f16x8 __attribute__((ext_vector_type(8)));
typedef float f32x4 __attribute__((ext_vector_type(4)));
typedef float f32x2 __attribute__((ext_vector_type(2)));
typedef unsigned short us8 __attribute__((ext_vector_type(8)));

#define H_DIM 256
#define OUT_DIM 256

__device__ inline float lrelu(float v) { return v > 0.f ? v : 0.01f * v; }

__device__ inline unsigned short f2h(float f) {
    _Float16 h = (_Float16)f;
    unsigned short u;
    __builtin_memcpy(&u, &h, 2);
    return u;
}

__device__ inline float h2f(unsigned short u) {
    _Float16 h;
    __builtin_memcpy(&h, &u, 2);
    return (float)h;
}

// ---------- prep kernels ----------

__global__ void k_gather_x0(const float* __restrict__ sst, const int* __restrict__ mask,
                            float* __restrict__ x0, int NT, int Nn, int F) {
    int v = blockIdx.x * 256 + threadIdx.x;
    if (v < NT) {
        int b = v / Nn;
        int i = v - b * Nn;
        x0[v] = sst[(size_t)b * F + mask[i]];
    }
}

// count + record each edge's rank within its dst bucket (coalesced store)
__global__ void k_count(const int* __restrict__ dst, int* __restrict__ cnt,
                        int* __restrict__ rank, int E) {
    int e = blockIdx.x * 256 + threadIdx.x;
    if (e < E) rank[e] = atomicAdd(&cnt[dst[e]], 1);
}

__global__ void k_dis(const int* __restrict__ cnt, float* __restrict__ dis, int NT) {
    int v = blockIdx.x * 256 + threadIdx.x;
    if (v < NT) dis[v] = rsqrtf((float)cnt[v] + 1.0f);
}

__global__ void k_scan_block(const int* __restrict__ cnt, int* __restrict__ bsum, int NT) {
    __shared__ int s[256];
    int i = blockIdx.x * 256 + threadIdx.x;
    s[threadIdx.x] = (i < NT) ? cnt[i] : 0;
    __syncthreads();
    for (int o = 128; o > 0; o >>= 1) {
        if (threadIdx.x < o) s[threadIdx.x] += s[threadIdx.x + o];
        __syncthreads();
    }
    if (threadIdx.x == 0) bsum[blockIdx.x] = s[0];
}

__global__ void k_scan_top(const int* __restrict__ bsum, int* __restrict__ bpre, int nb) {
    __shared__ int s[512];
    int t = threadIdx.x;
    int v = (t < nb) ? bsum[t] : 0;
    s[t] = v;
    __syncthreads();
    for (int o = 1; o < nb; o <<= 1) {
        int add = (t >= o) ? s[t - o] : 0;
        __syncthreads();
        s[t] += add;
        __syncthreads();
    }
    if (t < nb) bpre[t] = s[t] - v;   // exclusive
}

__global__ void k_scan_scatter(const int* __restrict__ cnt, const int* __restrict__ bpre,
                               int* __restrict__ startp, int NT) {
    __shared__ int s[256];
    int t = threadIdx.x;
    int i = blockIdx.x * 256 + t;
    int v = (i < NT) ? cnt[i] : 0;
    s[t] = v;
    __syncthreads();
    for (int o = 1; o < 256; o <<= 1) {
        int add = (t >= o) ? s[t - o] : 0;
        __syncthreads();
        s[t] += add;
        __syncthreads();
    }
    int excl = s[t] - v + bpre[blockIdx.x];
    if (i < NT) startp[i] = excl;
}

// fill: atomic-free; one packed 8B store per edge {src, cnorm bits}
__global__ void k_fill(const int* __restrict__ src, const int* __restrict__ dst,
                       const int* __restrict__ rank, const int* __restrict__ startp,
                       const float* __restrict__ dis, int2* __restrict__ ecsr, int E) {
    int e = blockIdx.x * 256 + threadIdx.x;
    if (e < E) {
        int s = src[e], d = dst[e];
        float nw = dis[s] * dis[d];
        int p = startp[d] + rank[e];
        ecsr[p] = make_int2(s, __float_as_int(nw));
    }
}

// ---- degree-sorted permutation (counting sort, 65 bins; order within bin arbitrary
//      but final output is order-invariant -> deterministic) ----

__global__ void k_dhist(const int* __restrict__ cnt, int* __restrict__ dcnt,
                        int* __restrict__ dloc, int NT) {
    __shared__ int h[65];
    __shared__ int basebuf[65];
    int t = threadIdx.x;
    if (t < 65) h[t] = 0;
    __syncthreads();
    int v = blockIdx.x * 256 + t;
    int bin = 0, lr = 0;
    if (v < NT) {
        int c = cnt[v];
        bin = c > 64 ? 64 : c;
        lr = atomicAdd(&h[bin], 1);
    }
    __syncthreads();
    if (t < 65) basebuf[t] = (h[t] > 0) ? atomicAdd(&dcnt[t], h[t]) : 0;
    __syncthreads();
    if (v < NT) dloc[v] = basebuf[bin] + lr;
}

__global__ void k_dscan(const int* __restrict__ dcnt, int* __restrict__ dstart) {
    if (threadIdx.x == 0) {
        int acc = 0;
        for (int b = 0; b < 65; b++) { dstart[b] = acc; acc += dcnt[b]; }
    }
}

__global__ void k_dfill(const int* __restrict__ cnt, const int* __restrict__ dloc,
                        const int* __restrict__ dstart, int* __restrict__ perm, int NT) {
    int v = blockIdx.x * 256 + threadIdx.x;
    if (v < NT) {
        int c = cnt[v];
        int bin = c > 64 ? 64 : c;
        perm[dstart[bin] + dloc[v]] = v;
    }
}

__global__ void k_prepW(const float* __restrict__ Ws, ushort_t* __restrict__ Wt, int total) {
    int idx = blockIdx.x * 256 + threadIdx.x;
    if (idx < total) {
        int l = idx >> 16;          // layer
        int rem = idx & 65535;
        int k = rem >> 8;           // input dim
        int n = rem & 255;          // output dim
        Wt[(l << 16) + (n << 8) + k] = f2h(Ws[idx]);
    }
}

// ---------- layer 1 (scalar input) ----------

__global__ void k_agg0(const float* __restrict__ x0, const int* __restrict__ startp,
                       const int* __restrict__ cnt, const int2* __restrict__ ecsr,
                       const float* __restrict__ dis, float* __restrict__ y0, int NT) {
    int v = blockIdx.x * 256 + threadIdx.x;
    if (v >= NT) return;
    float d = dis[v];
    float acc = d * d * x0[v];
    int s = startp[v], e = s + cnt[v];
    for (int i = s; i < e; i++) {
        int2 ec = ecsr[i];
        acc += __int_as_float(ec.y) * x0[ec.x];
    }
    y0[v] = acc;
}

__global__ void k_expand(const float* __restrict__ x0, const float* __restrict__ y0,
                         const float* __restrict__ W1, const float* __restrict__ b1,
                         ushort_t* __restrict__ xh, int NT) {
    int idx = blockIdx.x * 256 + threadIdx.x;      // one float4-worth each, NT*64 total
    int v = idx >> 6;
    int q = idx & 63;
    if (v >= NT) return;
    float xv = x0[v], yv = y0[v];
    float4 w = ((const float4*)W1)[q];
    float4 b = ((const float4*)b1)[q];
    ushort4 o;
    o.x = f2h(xv + lrelu(yv * w.x + b.x));
    o.y = f2h(xv + lrelu(yv * w.y + b.y));
    o.z = f2h(xv + lrelu(yv * w.z + b.z));
    o.w = f2h(xv + lrelu(yv * w.w + b.w));
    ((ushort4*)xh)[(size_t)v * 64 + q] = o;
}

// ---------- GEMM: z = xh @ W (fp16 MFMA, f32 acc, fp8 e4m3 out) ----------
// W held in REGISTERS (loaded once/block from L2); A staged once per 64-row tile
// for the FULL K=256 with XOR-swizzled LDS ([row][col^((row&7)<<4)]).
// Block: 256 thr = 4 waves, wave w owns cols [w*64, w*64+64) of all 64 rows.
// Grid-stride over NT/64 tiles. One barrier pair per tile.

__global__ __launch_bounds__(256) void k_gemm(const ushort_t* __restrict__ xh,
                                              const ushort_t* __restrict__ Wt,
                                              unsigned char* __restrict__ z, int NT) {
    __shared__ __align__(16) char AsRaw[64 * 512];    // 32 KB: 64 rows x 512B (swizzled)
    __shared__ __align__(16) char Rep[4][4096];       // 16 KB: per-wave fp8 repack
    int tid = threadIdx.x;
    int wave = tid >> 6, lane = tid & 63;
    int rl = lane & 15, hi = lane >> 4;               // hi in 0..3

    // ---- W fragments into registers: wave owns n-cols [wave*64, +64) ----
    f16x8 bf[4][8];
    #pragma unroll
    for (int ni = 0; ni < 4; ni++)
        #pragma unroll
        for (int c = 0; c < 8; c++)
            bf[ni][c] = *(const f16x8*)(Wt + (size_t)(wave * 64 + ni * 16 + rl) * 256
                                        + c * 32 + hi * 8);

    int ntiles = NT / 64;
    for (int t = blockIdx.x; t < ntiles; t += gridDim.x) {
        size_t rowbase = (size_t)t * 64;

        // ---- stage A tile: 64 rows x 256 fp16, swizzled write ----
        #pragma unroll
        for (int p = 0; p < 8; p++) {
            int idx = p * 256 + tid;          // 2048 chunks of 16B
            int row = idx >> 5;
            int colb = (idx & 31) * 16;
            uint4 vsrc = *(const uint4*)(xh + (rowbase + row) * H_DIM + (idx & 31) * 8);
            *(uint4*)(AsRaw + row * 512 + (colb ^ ((row & 7) << 4))) = vsrc;
        }
        __syncthreads();

        // ---- MFMA: 8 k-chunks x (4 mi x 4 ni) ----
        f32x4 acc[4][4];
        #pragma unroll
        for (int mi = 0; mi < 4; mi++)
            #pragma unroll
            for (int ni = 0; ni < 4; ni++)
                acc[mi][ni] = (f32x4){0.f, 0.f, 0.f, 0.f};

        #pragma unroll
        for (int c = 0; c < 8; c++) {
            f16x8 af[4];
            #pragma unroll
            for (int mi = 0; mi < 4; mi++) {
                int row = mi * 16 + rl;
                int colb = c * 64 + hi * 16;
                af[mi] = *(const f16x8*)(AsRaw + row * 512 + (colb ^ ((row & 7) << 4)));
            }
            #pragma unroll
            for (int mi = 0; mi < 4; mi++)
                #pragma unroll
                for (int ni = 0; ni < 4; ni++)
                    acc[mi][ni] = __builtin_amdgcn_mfma_f32_16x16x32_f16(
                        af[mi], bf[ni][c], acc[mi][ni], 0, 0, 0);
        }
        __syncthreads();   // As free for next tile's stage

        // ---- epilogue: fp8 pack -> per-wave LDS slice -> coalesced stores ----
        char* slice = &Rep[wave][0];
        #pragma unroll
        for (int mi = 0; mi < 4; mi++)
            #pragma unroll
            for (int ni = 0; ni < 4; ni++)
                #pragma unroll
                for (int r = 0; r < 4; r++) {
                    float vv = acc[mi][ni][r];
                    int pk = __builtin_amdgcn_cvt_pk_fp8_f32(vv, vv, 0, false);
                    slice[(mi * 16 + hi * 4 + r) * 64 + ni * 16 + rl] = (char)(pk & 0xFF);
                }
        #pragma unroll
        for (int p = 0; p < 4; p++) {
            uint4 val = *(const uint4*)(slice + p * 1024 + lane * 16);
            int lrow = p * 16 + (lane >> 2);
            int lcolb = (lane & 3) * 16;
            *(uint4*)(z + (rowbase + lrow) * 256 + wave * 64 + lcolb) = val;
        }
    }
}

// ---------- aggregate + bias + leaky + residual (in-place fp16 xh update) ----------
// TWO degree-matched nodes per wave (via perm); half-wave (32 lanes x 8B) per row.
// Metadata loaded once; per-edge broadcast via shfl. Unroll-8 -> 8 rows in flight.

__global__ void k_aggres(const unsigned char* __restrict__ z, const int* __restrict__ startp,
                         const int* __restrict__ cnt, const int2* __restrict__ ecsr,
                         const int* __restrict__ perm, const float* __restrict__ dis,
                         const float* __restrict__ bias, ushort_t* __restrict__ xh, int NT) {
    int tid = threadIdx.x;
    int wave = tid >> 6, lane = tid & 63;
    int h = lane >> 5, hl = lane & 31;
    int pidx = blockIdx.x * 8 + wave * 2 + h;
    if (pidx >= NT) return;
    int v = perm[pidx];

    float d = dis[v];
    int s = startp[v], cv = cnt[v];

    // metadata: lane h*32+k <- edge k of this half's node (one coalesced load)
    int nsrc = 0;
    float nw = 0.f;
    if (hl < cv) {
        int2 ec = ecsr[s + hl];
        nsrc = ec.x;
        nw = __int_as_float(ec.y);
    }

    // wave-uniform iteration bound = max of both halves' degrees (equal after sort)
    int cv0 = __shfl(cv, 0);
    int cv1 = __shfl(cv, 32);
    int cvmax = cv0 > cv1 ? cv0 : cv1;
    int inl = cvmax > 32 ? 32 : cvmax;
    int iters = (inl + 7) & ~7;

    // hoisted independent loads (in flight during gather)
    uint2 a = *(const uint2*)(z + (size_t)v * 256 + hl * 8);
    us8 xr = *(const us8*)(xh + (size_t)v * H_DIM + hl * 8);
    float4 bv0 = *(const float4*)(bias + hl * 8);
    float4 bv1 = *(const float4*)(bias + hl * 8 + 4);

    float sn = d * d;
    float acc[8];
    {
        f32x2 p0 = __builtin_amdgcn_cvt_pk_f32_fp8(a.x, false);
        f32x2 p1 = __builtin_amdgcn_cvt_pk_f32_fp8(a.x, true);
        f32x2 p2 = __builtin_amdgcn_cvt_pk_f32_fp8(a.y, false);
        f32x2 p3 = __builtin_amdgcn_cvt_pk_f32_fp8(a.y, true);
        acc[0] = sn * p0[0]; acc[1] = sn * p0[1];
        acc[2] = sn * p1[0]; acc[3] = sn * p1[1];
        acc[4] = sn * p2[0]; acc[5] = sn * p2[1];
        acc[6] = sn * p3[0]; acc[7] = sn * p3[1];
    }

    int base = h << 5;   // shfl source base for this half
    for (int k = 0; k < iters; k += 8) {
        int idx[8];
        float w[8];
        #pragma unroll
        for (int j = 0; j < 8; j++) {
            idx[j] = __shfl(nsrc, base + k + j);
            w[j]   = __shfl(nw,   base + k + j);
        }
        uint2 b[8];
        #pragma unroll
        for (int j = 0; j < 8; j++)
            b[j] = *(const uint2*)(z + (size_t)idx[j] * 256 + hl * 8);
        #pragma unroll
        for (int j = 0; j < 8; j++) {
            f32x2 p0 = __builtin_amdgcn_cvt_pk_f32_fp8(b[j].x, false);
            f32x2 p1 = __builtin_amdgcn_cvt_pk_f32_fp8(b[j].x, true);
            f32x2 p2 = __builtin_amdgcn_cvt_pk_f32_fp8(b[j].y, false);
            f32x2 p3 = __builtin_amdgcn_cvt_pk_f32_fp8(b[j].y, true);
            float ww = w[j];
            acc[0] += ww * p0[0]; acc[1] += ww * p0[1];
            acc[2] += ww * p1[0]; acc[3] += ww * p1[1];
            acc[4] += ww * p2[0]; acc[5] += ww * p2[1];
            acc[6] += ww * p3[0]; acc[7] += ww * p3[1];
        }
    }
    // overflow fallback (deg > 32 — statistically never for Poisson(8))
    for (int k = 32; k < cv; k++) {
        int2 ec = ecsr[s + k];
        float ww = __int_as_float(ec.y);
        uint2 bb = *(const uint2*)(z + (size_t)ec.x * 256 + hl * 8);
        f32x2 p0 = __builtin_amdgcn_cvt_pk_f32_fp8(bb.x, false);
        f32x2 p1 = __builtin_amdgcn_cvt_pk_f32_fp8(bb.x, true);
        f32x2 p2 = __builtin_amdgcn_cvt_pk_f32_fp8(bb.y, false);
        f32x2 p3 = __builtin_amdgcn_cvt_pk_f32_fp8(bb.y, true);
        acc[0] += ww * p0[0]; acc[1] += ww * p0[1];
        acc[2] += ww * p1[0]; acc[3] += ww * p1[1];
        acc[4] += ww * p2[0]; acc[5] += ww * p2[1];
        acc[6] += ww * p3[0]; acc[7] += ww * p3[1];
    }

    us8 o;
    o[0] = f2h(h2f(xr[0]) + lrelu(acc[0] + bv0.x));
    o[1] = f2h(h2f(xr[1]) + lrelu(acc[1] + bv0.y));
    o[2] = f2h(h2f(xr[2]) + lrelu(acc[2] + bv0.z));
    o[3] = f2h(h2f(xr[3]) + lrelu(acc[3] + bv0.w));
    o[4] = f2h(h2f(xr[4]) + lrelu(acc[4] + bv1.x));
    o[5] = f2h(h2f(xr[5]) + lrelu(acc[5] + bv1.y));
    o[6] = f2h(h2f(xr[6]) + lrelu(acc[6] + bv1.z));
    o[7] = f2h(h2f(xr[7]) + lrelu(acc[7] + bv1.w));
    *(us8*)(xh + (size_t)v * H_DIM + hl * 8) = o;
}

// ---------- pooling (3-stage tree) + head ----------

__global__ void k_pool1(const ushort_t* __restrict__ xh, float* __restrict__ partial) {
    __shared__ float s[4][256];
    int t = threadIdx.x;
    int w = t >> 6, lane = t & 63;
    size_t nodebase = (size_t)blockIdx.x * 64;
    float4 acc = make_float4(0.f, 0.f, 0.f, 0.f);
    for (int i = 0; i < 16; i++) {
        size_t node = nodebase + i * 4 + w;
        ushort4 v = *(const ushort4*)(xh + node * H_DIM + lane * 4);
        acc.x += h2f(v.x); acc.y += h2f(v.y); acc.z += h2f(v.z); acc.w += h2f(v.w);
    }
    *(float4*)&s[w][lane * 4] = acc;
    __syncthreads();
    float sum = s[0][t] + s[1][t] + s[2][t] + s[3][t];
    partial[(size_t)blockIdx.x * H_DIM + t] = sum;
}

__global__ void k_pool2(const float* __restrict__ partial, float* __restrict__ partial2,
                        int rowsPerChunk) {
    int blk = blockIdx.x, t = threadIdx.x;
    size_t rowbase = (size_t)blk * rowsPerChunk;
    float s = 0.f;
    for (int j = 0; j < rowsPerChunk; j++)
        s += partial[(rowbase + j) * H_DIM + t];
    partial2[(size_t)blk * H_DIM + t] = s;
}

__global__ void k_pool3(const float* __restrict__ partial2, float* __restrict__ pooled,
                        int chunksPerBatch, float inv) {
    int b = blockIdx.x, t = threadIdx.x;
    float s = 0.f;
    for (int j = 0; j < chunksPerBatch; j++)
        s += partial2[((size_t)b * chunksPerBatch + j) * H_DIM + t];
    pooled[b * H_DIM + t] = s * inv;
}

__global__ void k_head(const float* __restrict__ pooled, const float* __restrict__ Wh,
                       const float* __restrict__ bh, float* __restrict__ out) {
    int b = blockIdx.x, o = threadIdx.x;
    float acc = bh[o];
    for (int h = 0; h < H_DIM; h++) acc += pooled[b * H_DIM + h] * Wh[h * OUT_DIM + o];
    out[b * OUT_DIM + o] = acc;
}

// ---------- host ----------

extern "C" void kernel_launch(void* const* d_in, const int* in_sizes, int n_in,
                              void* d_out, int out_size, void* d_ws, size_t ws_size,
                              hipStream_t stream) {
    const float* sst  = (const float*)d_in[0];
    const int*   mask = (const int*)d_in[1];
    const int*   eidx = (const int*)d_in[2];
    const float* W1   = (const float*)d_in[3];
    const float* b1   = (const float*)d_in[4];
    const float* Ws   = (const float*)d_in[5];
    const float* bs   = (const float*)d_in[6];
    const float* Wh   = (const float*)d_in[7];
    const float* bh   = (const float*)d_in[8];

    const int B  = out_size / OUT_DIM;               // 2
    const int Nn = in_sizes[1];                      // 65536
    const int E  = in_sizes[2] / 2;                  // 1048576
    const int F  = in_sizes[0] / B;                  // 686364
    const int DEPTH = in_sizes[5] / (H_DIM * H_DIM); // 8
    const int NT = B * Nn;                           // 131072

    // workspace carve-up (256B aligned) — total ~126 MB
    size_t off = 0;
    char* base = (char*)d_ws;
    auto alloc = [&](size_t bytes) -> void* {
        void* p = base + off;
        off += (bytes + 255) & ~(size_t)255;
        return p;
    };
    ushort_t*      xh      = (ushort_t*)alloc((size_t)NT * H_DIM * 2);  // 67.1 MB fp16 residual
    unsigned char* zbuf    = (unsigned char*)alloc((size_t)NT * 256);   // 33.5 MB fp8
    float*    x0      = (float*)alloc((size_t)NT * 4);
    float*    y0      = (float*)alloc((size_t)NT * 4);
    int*      cnt     = (int*)alloc((size_t)NT * 4);
    int*      startp  = (int*)alloc((size_t)NT * 4);
    float*    dis     = (float*)alloc((size_t)NT * 4);
    int*      bsum    = (int*)alloc(4096);
    int*      bpre    = (int*)alloc(4096);
    int*      rank    = (int*)alloc((size_t)E * 4);                     // 4 MB
    int2*     ecsr    = (int2*)alloc((size_t)E * 8);                    // 8 MB
    int*      dcnt    = (int*)alloc(4096);
    int*      dstart  = (int*)alloc(4096);
    int*      dloc    = (int*)alloc((size_t)NT * 4);
    int*      perm    = (int*)alloc((size_t)NT * 4);
    ushort_t* Wt      = (ushort_t*)alloc((size_t)DEPTH * H_DIM * H_DIM * 2);  // 1 MB fp16
    float*    partial = (float*)alloc((size_t)(NT / 64) * H_DIM * 4);
    float*    partial2= (float*)alloc((size_t)64 * H_DIM * 4);
    float*    pooled  = (float*)alloc((size_t)B * H_DIM * 4);
    if (off > ws_size) return;   // workspace too small: fail visibly

    const int* esrc = eidx;
    const int* edst = eidx + E;

    dim3 blk(256);
    int gNT = (NT + 255) / 256;
    int gE  = (E + 255) / 256;
    int nb  = gNT;               // 512 scan blocks

    hipMemsetAsync(cnt, 0, (size_t)NT * 4, stream);
    hipMemsetAsync(dcnt, 0, 4096, stream);

    k_gather_x0<<<gNT, blk, 0, stream>>>(sst, mask, x0, NT, Nn, F);
    k_count<<<gE, blk, 0, stream>>>(edst, cnt, rank, E);
    k_dis<<<gNT, blk, 0, stream>>>(cnt, dis, NT);
    k_scan_block<<<nb, blk, 0, stream>>>(cnt, bsum, NT);
    k_scan_top<<<1, 512, 0, stream>>>(bsum, bpre, nb);
    k_scan_scatter<<<nb, blk, 0, stream>>>(cnt, bpre, startp, NT);
    k_fill<<<gE, blk, 0, stream>>>(esrc, edst, rank, startp, dis, ecsr, E);
    // degree-sorted permutation
    k_dhist<<<gNT, blk, 0, stream>>>(cnt, dcnt, dloc, NT);
    k_dscan<<<1, 64, 0, stream>>>(dcnt, dstart);
    k_dfill<<<gNT, blk, 0, stream>>>(cnt, dloc, dstart, perm, NT);
    k_prepW<<<(DEPTH * H_DIM * H_DIM + 255) / 256, blk, 0, stream>>>(Ws, Wt, DEPTH * H_DIM * H_DIM);

    // layer 1: scalar -> H (fp16 residual stream)
    k_agg0<<<gNT, blk, 0, stream>>>(x0, startp, cnt, ecsr, dis, y0, NT);
    k_expand<<<(NT * 64 + 255) / 256, blk, 0, stream>>>(x0, y0, W1, b1, xh, NT);

    // layers 2..9: z = xh@W (fp8 out), then aggregate+bias+leaky+residual into xh
    for (int l = 0; l < DEPTH; l++) {
        k_gemm<<<1024, blk, 0, stream>>>(xh, Wt + (size_t)l * H_DIM * H_DIM, zbuf, NT);
        k_aggres<<<NT / 8, blk, 0, stream>>>(zbuf, startp, cnt, ecsr, perm, dis,
                                             bs + (size_t)l * H_DIM, xh, NT);
    }

    // pool + head: 2048 -> 32 -> 2
    int pblocks = NT / 64;                 // 2048
    int chunksPerBatch = 16;
    int rowsPerChunk = (pblocks / B) / chunksPerBatch;   // 64
    k_pool1<<<pblocks, blk, 0, stream>>>(xh, partial);
    k_pool2<<<B * chunksPerBatch, blk, 0, stream>>>(partial, partial2, rowsPerChunk);
    k_pool3<<<B, blk, 0, stream>>>(partial2, pooled, chunksPerBatch, 1.0f / (float)Nn);
    k_head<<<B, blk, 0, stream>>>(pooled, Wh, bh, (float*)d_out);
}

// Round 15
// 852.320 us; speedup vs baseline: 1.1130x; 1.1130x over previous
//
#include <hip/hip_runtime.h>

typedef unsigned short ushort_t;
typedef _Float16 f16x8 __attribute__((ext_vector_type(8)));
typedef float f32x4 __attribute__((ext_vector_type(4)));
typedef float f32x2 __attribute__((ext_vector_type(2)));
typedef unsigned short us8 __attribute__((ext_vector_type(8)));

#define H_DIM 256
#define OUT_DIM 256

__device__ inline float lrelu(float v) { return v > 0.f ? v : 0.01f * v; }

__device__ inline unsigned short f2h(float f) {
    _Float16 h = (_Float16)f;
    unsigned short u;
    __builtin_memcpy(&u, &h, 2);
    return u;
}

__device__ inline float h2f(unsigned short u) {
    _Float16 h;
    __builtin_memcpy(&h, &u, 2);
    return (float)h;
}

// ---------- prep kernels ----------

__global__ void k_gather_x0(const float* __restrict__ sst, const int* __restrict__ mask,
                            float* __restrict__ x0, int NT, int Nn, int F) {
    int v = blockIdx.x * 256 + threadIdx.x;
    if (v < NT) {
        int b = v / Nn;
        int i = v - b * Nn;
        x0[v] = sst[(size_t)b * F + mask[i]];
    }
}

// count + record each edge's rank within its dst bucket (coalesced store)
__global__ void k_count(const int* __restrict__ dst, int* __restrict__ cnt,
                        int* __restrict__ rank, int E) {
    int e = blockIdx.x * 256 + threadIdx.x;
    if (e < E) rank[e] = atomicAdd(&cnt[dst[e]], 1);
}

__global__ void k_dis(const int* __restrict__ cnt, float* __restrict__ dis, int NT) {
    int v = blockIdx.x * 256 + threadIdx.x;
    if (v < NT) dis[v] = rsqrtf((float)cnt[v] + 1.0f);
}

__global__ void k_scan_block(const int* __restrict__ cnt, int* __restrict__ bsum, int NT) {
    __shared__ int s[256];
    int i = blockIdx.x * 256 + threadIdx.x;
    s[threadIdx.x] = (i < NT) ? cnt[i] : 0;
    __syncthreads();
    for (int o = 128; o > 0; o >>= 1) {
        if (threadIdx.x < o) s[threadIdx.x] += s[threadIdx.x + o];
        __syncthreads();
    }
    if (threadIdx.x == 0) bsum[blockIdx.x] = s[0];
}

__global__ void k_scan_top(const int* __restrict__ bsum, int* __restrict__ bpre, int nb) {
    __shared__ int s[512];
    int t = threadIdx.x;
    int v = (t < nb) ? bsum[t] : 0;
    s[t] = v;
    __syncthreads();
    for (int o = 1; o < nb; o <<= 1) {
        int add = (t >= o) ? s[t - o] : 0;
        __syncthreads();
        s[t] += add;
        __syncthreads();
    }
    if (t < nb) bpre[t] = s[t] - v;   // exclusive
}

__global__ void k_scan_scatter(const int* __restrict__ cnt, const int* __restrict__ bpre,
                               int* __restrict__ startp, int NT) {
    __shared__ int s[256];
    int t = threadIdx.x;
    int i = blockIdx.x * 256 + t;
    int v = (i < NT) ? cnt[i] : 0;
    s[t] = v;
    __syncthreads();
    for (int o = 1; o < 256; o <<= 1) {
        int add = (t >= o) ? s[t - o] : 0;
        __syncthreads();
        s[t] += add;
        __syncthreads();
    }
    int excl = s[t] - v + bpre[blockIdx.x];
    if (i < NT) startp[i] = excl;
}

// fill: atomic-free; one packed 8B store per edge {src, cnorm bits}
__global__ void k_fill(const int* __restrict__ src, const int* __restrict__ dst,
                       const int* __restrict__ rank, const int* __restrict__ startp,
                       const float* __restrict__ dis, int2* __restrict__ ecsr, int E) {
    int e = blockIdx.x * 256 + threadIdx.x;
    if (e < E) {
        int s = src[e], d = dst[e];
        float nw = dis[s] * dis[d];
        int p = startp[d] + rank[e];
        ecsr[p] = make_int2(s, __float_as_int(nw));
    }
}

__global__ void k_prepW(const float* __restrict__ Ws, ushort_t* __restrict__ Wt, int total) {
    int idx = blockIdx.x * 256 + threadIdx.x;
    if (idx < total) {
        int l = idx >> 16;          // layer
        int rem = idx & 65535;
        int k = rem >> 8;           // input dim
        int n = rem & 255;          // output dim
        Wt[(l << 16) + (n << 8) + k] = f2h(Ws[idx]);
    }
}

// ---------- layer 1 (scalar input) ----------

__global__ void k_agg0(const float* __restrict__ x0, const int* __restrict__ startp,
                       const int* __restrict__ cnt, const int2* __restrict__ ecsr,
                       const float* __restrict__ dis, float* __restrict__ y0, int NT) {
    int v = blockIdx.x * 256 + threadIdx.x;
    if (v >= NT) return;
    float d = dis[v];
    float acc = d * d * x0[v];
    int s = startp[v], e = s + cnt[v];
    for (int i = s; i < e; i++) {
        int2 ec = ecsr[i];
        acc += __int_as_float(ec.y) * x0[ec.x];
    }
    y0[v] = acc;
}

__global__ void k_expand(const float* __restrict__ x0, const float* __restrict__ y0,
                         const float* __restrict__ W1, const float* __restrict__ b1,
                         ushort_t* __restrict__ xh, int NT) {
    int idx = blockIdx.x * 256 + threadIdx.x;      // one float4-worth each, NT*64 total
    int v = idx >> 6;
    int q = idx & 63;
    if (v >= NT) return;
    float xv = x0[v], yv = y0[v];
    float4 w = ((const float4*)W1)[q];
    float4 b = ((const float4*)b1)[q];
    ushort4 o;
    o.x = f2h(xv + lrelu(yv * w.x + b.x));
    o.y = f2h(xv + lrelu(yv * w.y + b.y));
    o.z = f2h(xv + lrelu(yv * w.z + b.z));
    o.w = f2h(xv + lrelu(yv * w.w + b.w));
    ((ushort4*)xh)[(size_t)v * 64 + q] = o;
}

// ---------- GEMM: z = xh @ W (fp16 MFMA, f32 acc, fp8 e4m3 out) ----------
// W held in REGISTERS (loaded once/block from L2); A staged once per 64-row tile
// for the FULL K=256 with XOR-swizzled LDS ([row][col^((row&7)<<4)]).
// Block: 256 thr = 4 waves, wave w owns cols [w*64, w*64+64) of all 64 rows.
// Grid-stride over NT/64 tiles. One barrier pair per tile.

__global__ __launch_bounds__(256) void k_gemm(const ushort_t* __restrict__ xh,
                                              const ushort_t* __restrict__ Wt,
                                              unsigned char* __restrict__ z, int NT) {
    __shared__ __align__(16) char AsRaw[64 * 512];    // 32 KB: 64 rows x 512B (swizzled)
    __shared__ __align__(16) char Rep[4][4096];       // 16 KB: per-wave fp8 repack
    int tid = threadIdx.x;
    int wave = tid >> 6, lane = tid & 63;
    int rl = lane & 15, hi = lane >> 4;               // hi in 0..3

    // ---- W fragments into registers: wave owns n-cols [wave*64, +64) ----
    f16x8 bf[4][8];
    #pragma unroll
    for (int ni = 0; ni < 4; ni++)
        #pragma unroll
        for (int c = 0; c < 8; c++)
            bf[ni][c] = *(const f16x8*)(Wt + (size_t)(wave * 64 + ni * 16 + rl) * 256
                                        + c * 32 + hi * 8);

    int ntiles = NT / 64;
    for (int t = blockIdx.x; t < ntiles; t += gridDim.x) {
        size_t rowbase = (size_t)t * 64;

        // ---- stage A tile: 64 rows x 256 fp16, swizzled write ----
        #pragma unroll
        for (int p = 0; p < 8; p++) {
            int idx = p * 256 + tid;          // 2048 chunks of 16B
            int row = idx >> 5;
            int colb = (idx & 31) * 16;
            uint4 vsrc = *(const uint4*)(xh + (rowbase + row) * H_DIM + (idx & 31) * 8);
            *(uint4*)(AsRaw + row * 512 + (colb ^ ((row & 7) << 4))) = vsrc;
        }
        __syncthreads();

        // ---- MFMA: 8 k-chunks x (4 mi x 4 ni) ----
        f32x4 acc[4][4];
        #pragma unroll
        for (int mi = 0; mi < 4; mi++)
            #pragma unroll
            for (int ni = 0; ni < 4; ni++)
                acc[mi][ni] = (f32x4){0.f, 0.f, 0.f, 0.f};

        #pragma unroll
        for (int c = 0; c < 8; c++) {
            f16x8 af[4];
            #pragma unroll
            for (int mi = 0; mi < 4; mi++) {
                int row = mi * 16 + rl;
                int colb = c * 64 + hi * 16;
                af[mi] = *(const f16x8*)(AsRaw + row * 512 + (colb ^ ((row & 7) << 4)));
            }
            #pragma unroll
            for (int mi = 0; mi < 4; mi++)
                #pragma unroll
                for (int ni = 0; ni < 4; ni++)
                    acc[mi][ni] = __builtin_amdgcn_mfma_f32_16x16x32_f16(
                        af[mi], bf[ni][c], acc[mi][ni], 0, 0, 0);
        }
        __syncthreads();   // As free for next tile's stage

        // ---- epilogue: fp8 pack -> per-wave LDS slice -> coalesced stores ----
        char* slice = &Rep[wave][0];
        #pragma unroll
        for (int mi = 0; mi < 4; mi++)
            #pragma unroll
            for (int ni = 0; ni < 4; ni++)
                #pragma unroll
                for (int r = 0; r < 4; r++) {
                    float vv = acc[mi][ni][r];
                    int pk = __builtin_amdgcn_cvt_pk_fp8_f32(vv, vv, 0, false);
                    slice[(mi * 16 + hi * 4 + r) * 64 + ni * 16 + rl] = (char)(pk & 0xFF);
                }
        #pragma unroll
        for (int p = 0; p < 4; p++) {
            uint4 val = *(const uint4*)(slice + p * 1024 + lane * 16);
            int lrow = p * 16 + (lane >> 2);
            int lcolb = (lane & 3) * 16;
            *(uint4*)(z + (rowbase + lrow) * 256 + wave * 64 + lcolb) = val;
        }
    }
}

// ---------- aggregate + bias + leaky + residual (in-place fp16 xh update) ----------
// TWO nodes per wave (natural order — no perm; preserves index-space locality).
// Half-wave (32 lanes x 8B) per 256B fp8 row. Metadata loaded once, shfl broadcast.
// Software-pipelined: prefetch next 4 rows while FMA-ing current 4 (8 in flight).

__global__ void k_aggres(const unsigned char* __restrict__ z, const int* __restrict__ startp,
                         const int* __restrict__ cnt, const int2* __restrict__ ecsr,
                         const float* __restrict__ dis, const float* __restrict__ bias,
                         ushort_t* __restrict__ xh, int NT) {
    int tid = threadIdx.x;
    int wave = tid >> 6, lane = tid & 63;
    int h = lane >> 5, hl = lane & 31;
    int v = blockIdx.x * 8 + wave * 2 + h;
    if (v >= NT) return;

    float d = dis[v];
    int s = startp[v], cv = cnt[v];

    // metadata: lane h*32+k <- edge k of this half's node (one coalesced load)
    int nsrc = 0;
    float nw = 0.f;
    if (hl < cv) {
        int2 ec = ecsr[s + hl];
        nsrc = ec.x;
        nw = __int_as_float(ec.y);
    }

    // wave-uniform iteration bound = max of both halves' degrees
    int cv0 = __shfl(cv, 0);
    int cv1 = __shfl(cv, 32);
    int cvmax = cv0 > cv1 ? cv0 : cv1;
    int inl = cvmax > 32 ? 32 : cvmax;
    int iters = (inl + 3) & ~3;

    // hoisted independent loads (in flight during gather)
    uint2 a = *(const uint2*)(z + (size_t)v * 256 + hl * 8);
    us8 xr = *(const us8*)(xh + (size_t)v * H_DIM + hl * 8);
    float4 bv0 = *(const float4*)(bias + hl * 8);
    float4 bv1 = *(const float4*)(bias + hl * 8 + 4);

    float sn = d * d;
    float acc[8];
    {
        f32x2 p0 = __builtin_amdgcn_cvt_pk_f32_fp8(a.x, false);
        f32x2 p1 = __builtin_amdgcn_cvt_pk_f32_fp8(a.x, true);
        f32x2 p2 = __builtin_amdgcn_cvt_pk_f32_fp8(a.y, false);
        f32x2 p3 = __builtin_amdgcn_cvt_pk_f32_fp8(a.y, true);
        acc[0] = sn * p0[0]; acc[1] = sn * p0[1];
        acc[2] = sn * p1[0]; acc[3] = sn * p1[1];
        acc[4] = sn * p2[0]; acc[5] = sn * p2[1];
        acc[6] = sn * p3[0]; acc[7] = sn * p3[1];
    }

    int base = h << 5;   // shfl source base for this half
    // prologue: batch 0 in flight
    uint2 b[4];
    float w[4];
    #pragma unroll
    for (int j = 0; j < 4; j++) {
        int ii = __shfl(nsrc, base + j);
        w[j]   = __shfl(nw,   base + j);
        b[j] = *(const uint2*)(z + (size_t)ii * 256 + hl * 8);
    }
    for (int k = 0; k < iters; k += 4) {
        uint2 nb[4];
        float nwt[4];
        bool more = (k + 4) < iters;   // wave-uniform
        if (more) {
            #pragma unroll
            for (int j = 0; j < 4; j++) {
                int ii = __shfl(nsrc, base + k + 4 + j);
                nwt[j] = __shfl(nw,   base + k + 4 + j);
                nb[j] = *(const uint2*)(z + (size_t)ii * 256 + hl * 8);
            }
        }
        #pragma unroll
        for (int j = 0; j < 4; j++) {
            f32x2 p0 = __builtin_amdgcn_cvt_pk_f32_fp8(b[j].x, false);
            f32x2 p1 = __builtin_amdgcn_cvt_pk_f32_fp8(b[j].x, true);
            f32x2 p2 = __builtin_amdgcn_cvt_pk_f32_fp8(b[j].y, false);
            f32x2 p3 = __builtin_amdgcn_cvt_pk_f32_fp8(b[j].y, true);
            float ww = w[j];
            acc[0] += ww * p0[0]; acc[1] += ww * p0[1];
            acc[2] += ww * p1[0]; acc[3] += ww * p1[1];
            acc[4] += ww * p2[0]; acc[5] += ww * p2[1];
            acc[6] += ww * p3[0]; acc[7] += ww * p3[1];
        }
        if (more) {
            #pragma unroll
            for (int j = 0; j < 4; j++) { b[j] = nb[j]; w[j] = nwt[j]; }
        }
    }
    // overflow fallback (deg > 32 — statistically never for Poisson(8))
    for (int k = 32; k < cv; k++) {
        int2 ec = ecsr[s + k];
        float ww = __int_as_float(ec.y);
        uint2 bb = *(const uint2*)(z + (size_t)ec.x * 256 + hl * 8);
        f32x2 p0 = __builtin_amdgcn_cvt_pk_f32_fp8(bb.x, false);
        f32x2 p1 = __builtin_amdgcn_cvt_pk_f32_fp8(bb.x, true);
        f32x2 p2 = __builtin_amdgcn_cvt_pk_f32_fp8(bb.y, false);
        f32x2 p3 = __builtin_amdgcn_cvt_pk_f32_fp8(bb.y, true);
        acc[0] += ww * p0[0]; acc[1] += ww * p0[1];
        acc[2] += ww * p1[0]; acc[3] += ww * p1[1];
        acc[4] += ww * p2[0]; acc[5] += ww * p2[1];
        acc[6] += ww * p3[0]; acc[7] += ww * p3[1];
    }

    us8 o;
    o[0] = f2h(h2f(xr[0]) + lrelu(acc[0] + bv0.x));
    o[1] = f2h(h2f(xr[1]) + lrelu(acc[1] + bv0.y));
    o[2] = f2h(h2f(xr[2]) + lrelu(acc[2] + bv0.z));
    o[3] = f2h(h2f(xr[3]) + lrelu(acc[3] + bv0.w));
    o[4] = f2h(h2f(xr[4]) + lrelu(acc[4] + bv1.x));
    o[5] = f2h(h2f(xr[5]) + lrelu(acc[5] + bv1.y));
    o[6] = f2h(h2f(xr[6]) + lrelu(acc[6] + bv1.z));
    o[7] = f2h(h2f(xr[7]) + lrelu(acc[7] + bv1.w));
    *(us8*)(xh + (size_t)v * H_DIM + hl * 8) = o;
}

// ---------- pooling (3-stage tree) + head ----------

__global__ void k_pool1(const ushort_t* __restrict__ xh, float* __restrict__ partial) {
    __shared__ float s[4][256];
    int t = threadIdx.x;
    int w = t >> 6, lane = t & 63;
    size_t nodebase = (size_t)blockIdx.x * 64;
    float4 acc = make_float4(0.f, 0.f, 0.f, 0.f);
    for (int i = 0; i < 16; i++) {
        size_t node = nodebase + i * 4 + w;
        ushort4 v = *(const ushort4*)(xh + node * H_DIM + lane * 4);
        acc.x += h2f(v.x); acc.y += h2f(v.y); acc.z += h2f(v.z); acc.w += h2f(v.w);
    }
    *(float4*)&s[w][lane * 4] = acc;
    __syncthreads();
    float sum = s[0][t] + s[1][t] + s[2][t] + s[3][t];
    partial[(size_t)blockIdx.x * H_DIM + t] = sum;
}

__global__ void k_pool2(const float* __restrict__ partial, float* __restrict__ partial2,
                        int rowsPerChunk) {
    int blk = blockIdx.x, t = threadIdx.x;
    size_t rowbase = (size_t)blk * rowsPerChunk;
    float s = 0.f;
    for (int j = 0; j < rowsPerChunk; j++)
        s += partial[(rowbase + j) * H_DIM + t];
    partial2[(size_t)blk * H_DIM + t] = s;
}

__global__ void k_pool3(const float* __restrict__ partial2, float* __restrict__ pooled,
                        int chunksPerBatch, float inv) {
    int b = blockIdx.x, t = threadIdx.x;
    float s = 0.f;
    for (int j = 0; j < chunksPerBatch; j++)
        s += partial2[((size_t)b * chunksPerBatch + j) * H_DIM + t];
    pooled[b * H_DIM + t] = s * inv;
}

__global__ void k_head(const float* __restrict__ pooled, const float* __restrict__ Wh,
                       const float* __restrict__ bh, float* __restrict__ out) {
    int b = blockIdx.x, o = threadIdx.x;
    float acc = bh[o];
    for (int h = 0; h < H_DIM; h++) acc += pooled[b * H_DIM + h] * Wh[h * OUT_DIM + o];
    out[b * OUT_DIM + o] = acc;
}

// ---------- host ----------

extern "C" void kernel_launch(void* const* d_in, const int* in_sizes, int n_in,
                              void* d_out, int out_size, void* d_ws, size_t ws_size,
                              hipStream_t stream) {
    const float* sst  = (const float*)d_in[0];
    const int*   mask = (const int*)d_in[1];
    const int*   eidx = (const int*)d_in[2];
    const float* W1   = (const float*)d_in[3];
    const float* b1   = (const float*)d_in[4];
    const float* Ws   = (const float*)d_in[5];
    const float* bs   = (const float*)d_in[6];
    const float* Wh   = (const float*)d_in[7];
    const float* bh   = (const float*)d_in[8];

    const int B  = out_size / OUT_DIM;               // 2
    const int Nn = in_sizes[1];                      // 65536
    const int E  = in_sizes[2] / 2;                  // 1048576
    const int F  = in_sizes[0] / B;                  // 686364
    const int DEPTH = in_sizes[5] / (H_DIM * H_DIM); // 8
    const int NT = B * Nn;                           // 131072

    // workspace carve-up (256B aligned) — total ~125 MB
    size_t off = 0;
    char* base = (char*)d_ws;
    auto alloc = [&](size_t bytes) -> void* {
        void* p = base + off;
        off += (bytes + 255) & ~(size_t)255;
        return p;
    };
    ushort_t*      xh      = (ushort_t*)alloc((size_t)NT * H_DIM * 2);  // 67.1 MB fp16 residual
    unsigned char* zbuf    = (unsigned char*)alloc((size_t)NT * 256);   // 33.5 MB fp8
    float*    x0      = (float*)alloc((size_t)NT * 4);
    float*    y0      = (float*)alloc((size_t)NT * 4);
    int*      cnt     = (int*)alloc((size_t)NT * 4);
    int*      startp  = (int*)alloc((size_t)NT * 4);
    float*    dis     = (float*)alloc((size_t)NT * 4);
    int*      bsum    = (int*)alloc(4096);
    int*      bpre    = (int*)alloc(4096);
    int*      rank    = (int*)alloc((size_t)E * 4);                     // 4 MB
    int2*     ecsr    = (int2*)alloc((size_t)E * 8);                    // 8 MB
    ushort_t* Wt      = (ushort_t*)alloc((size_t)DEPTH * H_DIM * H_DIM * 2);  // 1 MB fp16
    float*    partial = (float*)alloc((size_t)(NT / 64) * H_DIM * 4);
    float*    partial2= (float*)alloc((size_t)64 * H_DIM * 4);
    float*    pooled  = (float*)alloc((size_t)B * H_DIM * 4);
    if (off > ws_size) return;   // workspace too small: fail visibly

    const int* esrc = eidx;
    const int* edst = eidx + E;

    dim3 blk(256);
    int gNT = (NT + 255) / 256;
    int gE  = (E + 255) / 256;
    int nb  = gNT;               // 512 scan blocks

    hipMemsetAsync(cnt, 0, (size_t)NT * 4, stream);

    k_gather_x0<<<gNT, blk, 0, stream>>>(sst, mask, x0, NT, Nn, F);
    k_count<<<gE, blk, 0, stream>>>(edst, cnt, rank, E);
    k_dis<<<gNT, blk, 0, stream>>>(cnt, dis, NT);
    k_scan_block<<<nb, blk, 0, stream>>>(cnt, bsum, NT);
    k_scan_top<<<1, 512, 0, stream>>>(bsum, bpre, nb);
    k_scan_scatter<<<nb, blk, 0, stream>>>(cnt, bpre, startp, NT);
    k_fill<<<gE, blk, 0, stream>>>(esrc, edst, rank, startp, dis, ecsr, E);
    k_prepW<<<(DEPTH * H_DIM * H_DIM + 255) / 256, blk, 0, stream>>>(Ws, Wt, DEPTH * H_DIM * H_DIM);

    // layer 1: scalar -> H (fp16 residual stream)
    k_agg0<<<gNT, blk, 0, stream>>>(x0, startp, cnt, ecsr, dis, y0, NT);
    k_expand<<<(NT * 64 + 255) / 256, blk, 0, stream>>>(x0, y0, W1, b1, xh, NT);

    // layers 2..9: z = xh@W (fp8 out), then aggregate+bias+leaky+residual into xh
    for (int l = 0; l < DEPTH; l++) {
        k_gemm<<<512, blk, 0, stream>>>(xh, Wt + (size_t)l * H_DIM * H_DIM, zbuf, NT);
        k_aggres<<<NT / 8, blk, 0, stream>>>(zbuf, startp, cnt, ecsr, dis,
                                             bs + (size_t)l * H_DIM, xh, NT);
    }

    // pool + head: 2048 -> 32 -> 2
    int pblocks = NT / 64;                 // 2048
    int chunksPerBatch = 16;
    int rowsPerChunk = (pblocks / B) / chunksPerBatch;   // 64
    k_pool1<<<pblocks, blk, 0, stream>>>(xh, partial);
    k_pool2<<<B * chunksPerBatch, blk, 0, stream>>>(partial, partial2, rowsPerChunk);
    k_pool3<<<B, blk, 0, stream>>>(partial2, pooled, chunksPerBatch, 1.0f / (float)Nn);
    k_head<<<B, blk, 0, stream>>>(pooled, Wh, bh, (float*)d_out);
}